// Round 5
// baseline (10650.201 us; speedup 1.0000x reference)
//
#include <hip/hip_runtime.h>

// ---------------------------------------------------------------------------
// GLIFR RSNN on MI355X — round 10: XCD-LOCAL EXCHANGE (sc0/L2) + agent mirror.
//
// History:
//   r1 (PASSED, 11.75ms): 8 WGs/batch, cooperative, counter barrier.
//   r2/r3/r4/r7 (GHOST): cooperative launch + modified sync -> kernel never
//      ran. Plain launches have never ghosted. Cooperative path ABANDONED.
//   r5 (PASSED, 2290us recur): counter protocol, 4 serial RTTs/step.
//   r6 (REGRESSED, 2465us): phase-split; no slack to hide work in.
//   r8 (DIED): VGPR math error (Wr slice needs 128 regs/thread at M=64;
//      bigger M-slices don't fit — the 8-WG split is forced by the regfile).
//   r9 (PASSED, 2590us): tagged 8B data-is-flag at agent scope. WORSE.
//      Counters: FETCH 405->644MB, WRITE 328->640MB => every exchange access
//      misses L2 (agent atomics resolve at MALL, ~1000+cy RTT) and 65536
//      hot-pollers congest it. Agent-scope protocol space is EXHAUSTED.
//   r10 (this): change the PHYSICS, not the protocol. Place all 8 WGs of a
//      batch on ONE XCD (dispatch is round-robin: XCD = bid&7 — same mapping
//      HK's chiplet swizzle exploits): b=(bid&7)*4+(bid>>6), s=(bid>>3)&7.
//      Exchange via sc0-scope 8B tagged words: CDNA L1 is write-through, so
//      a store lands in the SHARED per-XCD L2; an sc0 load bypasses L1 and
//      HITS L2 -> ~250cy RTT instead of ~1000+. Tag makes the store its own
//      flag (r9's proven self-cleaning scheme: tag=t+1, slot=t&1, ws-poison
//      0xAAAAAAAA never matches a tag in [1,1000]).
//      SAFETY (placement is a perf heuristic, never a correctness input):
//      producers dual-store fast (sc0) + mirror (agent atomic, r9's proven
//      path). Consumers poll fast; after FAST_CAP failed rounds they flip
//      STICKY to the mirror. Hard cap -> visible failure, never a hang.
//
// NOTE (r2/r3 lesson, keep): fp32 S is EXACTLY 0.0 for strongly inhibited
// neurons (V ~ -1050 -> __expf overflow -> 20/inf = 0), identically in the
// jax reference. 0x00000000 output words are legitimate.
// ---------------------------------------------------------------------------

#define T_STEPS 1000
#define NB 32
#define N0 256
#define N1 512

#define FAST_CAP 4096     // fast-poll rounds before sticky fallback (~0.5ms once)
#define HARD_CAP (1 << 17) // absolute bound: worst case fast visible failure

// fp32 constants, folded exactly like the reference's python-float scalars
#define C_SYN_D 0.95f                      // 1 - DT*KSYN
#define C_SYN_I 0.05f                      // DT*KSYN
#define C_V_D   0.99f                      // 1 - DT*KM
#define C_KMR   0.0010604453870625663f     // DT*KM*R
#define C_TH    10.986122886681098f        // SIGMA_V * log((20-5)/5)
#define C_A0_D  0.99985f                   // 1 - DT*0.003
#define C_A0_I  (-0.459f)                  // -9.18*1.0*DT
#define C_A1_D  0.995f                     // 1 - DT*0.1
#define C_A1_I  (-9.947f)                  // -198.94*1.0*DT

__device__ __forceinline__ float glif_S(float V) {
  // 20 * sigmoid((V - TH)/10)
  return 20.0f / (1.0f + __expf((C_TH - V) * 0.1f));
}

// ---------------------------------------------------------------------------
// Kernel A: layer-0 scan (r5-verbatim, proven). grid = 128 x 64.
// ---------------------------------------------------------------------------
__global__ __launch_bounds__(64)
void layer0_scan(const float* __restrict__ x, float* __restrict__ S0) {
  const int g = blockIdx.x * 64 + threadIdx.x;
  float V = 0.f, a0 = 0.f, a1 = 0.f, Is = 0.f;
  float xb[8];
#pragma unroll
  for (int i = 0; i < 8; ++i) xb[i] = x[i * (NB * N0) + g];
#pragma unroll 1
  for (int tb = 0; tb < T_STEPS / 8; ++tb) {
#pragma unroll
    for (int u = 0; u < 8; ++u) {
      const int t = tb * 8 + u;
      const float xi = xb[u];
      const int tf = t + 8;
      if (tf < T_STEPS) xb[u] = x[tf * (NB * N0) + g];
      Is = fmaf(Is, C_SYN_D, C_SYN_I * xi);
      V  = fmaf(V, C_V_D, C_KMR * (Is + a0 + a1));
      const float S = glif_S(V);
      a0 = fmaf(a0, C_A0_D, C_A0_I * S);
      a1 = fmaf(a1, C_A1_D, C_A1_I * S);
      S0[t * (NB * N0) + g] = S;
    }
  }
}

// ---------------------------------------------------------------------------
// Kernel C: recurrence. grid = 256 x 256, PLAIN launch.
// XCD-local mapping: b = (bid&7)*4 + (bid>>6), s = (bid>>3)&7 — all 8 slices
// of a batch share bid&7 == b>>2, i.e. one XCD under round-robin dispatch.
// Per-WG compute core (weights in regs, LDS staging, shfl reduce, GLIF) is
// r5/r9-verbatim. Exchange: xf/xs [slot][b][n] as u64 {tag<<32 | fp32 bits};
// spb_t -> slot t&1, tag t+1; consumer at step t polls slot (t-1)&1, tag t.
// ---------------------------------------------------------------------------
__global__ __launch_bounds__(256, 1)
void rsnn_recur(const float* __restrict__ W1, const float* __restrict__ Wr,
                const float* __restrict__ S0, float* __restrict__ out,
                unsigned long long* __restrict__ xf,
                unsigned long long* __restrict__ xs) {
  const int bid = blockIdx.x;
  const int b   = (bid & 7) * 4 + (bid >> 6);   // batch  (XCD-local group)
  const int s   = (bid >> 3) & 7;               // m-slice
  const int tid = threadIdx.x;
  const int mg  = tid >> 4;
  const int kc  = tid & 15;
  const int mBase = s * 64 + mg * 4;

  __shared__ float actS[16 * 36];   // 512 spb values, padded (r5 layout)
  __shared__ float actO[16 * 20];   // 256 S0 values, padded (r5 layout)

  // --- one-time weight load into registers (r5-verbatim) ---
  float4 wr4[4][8];
  float4 w14[4][4];
#pragma unroll
  for (int i = 0; i < 4; ++i) {
    const float4* rw = (const float4*)(Wr + (size_t)(mBase + i) * N1 + kc * 32);
#pragma unroll
    for (int j = 0; j < 8; ++j) wr4[i][j] = rw[j];
    const float4* r1 = (const float4*)(W1 + (size_t)(mBase + i) * N0 + kc * 16);
#pragma unroll
    for (int j = 0; j < 4; ++j) w14[i][j] = r1[j];
  }

  float V[4]   = {0.f, 0.f, 0.f, 0.f};
  float A0v[4] = {0.f, 0.f, 0.f, 0.f};
  float A1v[4] = {0.f, 0.f, 0.f, 0.f};
  float Is[4]  = {0.f, 0.f, 0.f, 0.f};

  bool gave_up = false;   // after one hard cap, never block again
  bool slow0 = false, slow1 = false;  // sticky fast->mirror fallback per word

#pragma unroll 1
  for (int t = 0; t < T_STEPS; ++t) {
    // ---- stage previous activations into LDS ----
    if (t == 0) {
      actS[(tid >> 5) * 36 + (tid & 31)] = 0.f;
      {
        const int k = tid + 256;
        actS[(k >> 5) * 36 + (k & 31)] = 0.f;
      }
      actO[(tid >> 4) * 20 + (tid & 15)] = 0.f;
    } else {
      // issue the (plain, cached) S0 load first so it flies under the poll
      const float v2 = S0[(size_t)(t - 1) * (NB * N0) + b * N0 + tid];
      const size_t xoff = (size_t)((t - 1) & 1) * (NB * N1) + (size_t)b * N1;
      const unsigned long long af =
          (unsigned long long)(uintptr_t)(xf + xoff + tid);  // word0; word1 at +2048B
      const unsigned long long* ps = xs + xoff;               // mirror (agent)
      const unsigned tg = (unsigned)t;     // tag of spb_{t-1}
      unsigned long long w0 = 0ull, w1 = 0ull;
      bool r0 = false, r1 = false;
      int iter = gave_up ? (HARD_CAP + 1) : 0;
      for (;;) {
        // fast path: sc0 load = bypass L1, HIT the shared per-XCD L2.
        if (!r0) {
          if (!slow0) {
            asm volatile("global_load_dwordx2 %0, %1, off sc0"
                         : "=v"(w0) : "v"(af) : "memory");
          } else {
            w0 = __hip_atomic_load(ps + tid, __ATOMIC_RELAXED,
                                   __HIP_MEMORY_SCOPE_AGENT);
          }
        }
        if (!r1) {
          if (!slow1) {
            asm volatile("global_load_dwordx2 %0, %1, off offset:2048 sc0"
                         : "=v"(w1) : "v"(af) : "memory");
          } else {
            w1 = __hip_atomic_load(ps + tid + 256, __ATOMIC_RELAXED,
                                   __HIP_MEMORY_SCOPE_AGENT);
          }
        }
        asm volatile("s_waitcnt vmcnt(0)" ::: "memory");
        if (!r0) r0 = ((unsigned)(w0 >> 32) == tg);
        if (!r1) r1 = ((unsigned)(w1 >> 32) == tg);
        if (r0 && r1) break;
        ++iter;
        if (iter == FAST_CAP) {    // placement heuristic failed for this word:
          slow0 = slow0 || !r0;    // flip sticky to the agent mirror (proven
          slow1 = slow1 || !r1;    // r9 path; correct under ANY placement).
        }
        if (iter > HARD_CAP) { gave_up = true; break; }  // visible, no hang
        __builtin_amdgcn_s_sleep(1);   // pace polls (~64cy)
      }
      actS[(tid >> 5) * 36 + (tid & 31)] = __uint_as_float((unsigned)w0);
      {
        const int k = tid + 256;
        actS[(k >> 5) * 36 + (k & 31)] = __uint_as_float((unsigned)w1);
      }
      actO[(tid >> 4) * 20 + (tid & 15)] = v2;
    }
    __syncthreads();  // staging visible

    // ---- partial dot products (r5-verbatim) ----
    float h2a[4] = {0.f, 0.f, 0.f, 0.f};
    float h1a[4] = {0.f, 0.f, 0.f, 0.f};
    const float4* aS4 = (const float4*)actS;
    const float4* aO4 = (const float4*)actO;
#pragma unroll
    for (int j = 0; j < 8; ++j) {
      const float4 a = aS4[kc * 9 + j];
#pragma unroll
      for (int i = 0; i < 4; ++i) {
        h2a[i] = fmaf(wr4[i][j].x, a.x, h2a[i]);
        h2a[i] = fmaf(wr4[i][j].y, a.y, h2a[i]);
        h2a[i] = fmaf(wr4[i][j].z, a.z, h2a[i]);
        h2a[i] = fmaf(wr4[i][j].w, a.w, h2a[i]);
      }
    }
#pragma unroll
    for (int j = 0; j < 4; ++j) {
      const float4 a = aO4[kc * 5 + j];
#pragma unroll
      for (int i = 0; i < 4; ++i) {
        h1a[i] = fmaf(w14[i][j].x, a.x, h1a[i]);
        h1a[i] = fmaf(w14[i][j].y, a.y, h1a[i]);
        h1a[i] = fmaf(w14[i][j].z, a.z, h1a[i]);
        h1a[i] = fmaf(w14[i][j].w, a.w, h1a[i]);
      }
    }
    __syncthreads();  // all LDS reads done; next iteration may overwrite

    // ---- reduce across the 16 k-chunks (r5-verbatim order) ----
#pragma unroll
    for (int mask = 1; mask <= 8; mask <<= 1) {
#pragma unroll
      for (int i = 0; i < 4; ++i) {
        h2a[i] += __shfl_xor(h2a[i], mask, 64);
        h1a[i] += __shfl_xor(h1a[i], mask, 64);
      }
    }

    // ---- owner lanes: GLIF A (h1) then GLIF B (h2) — r5-verbatim math ----
    if (kc == 0) {
      float spa[4], spb[4];
#pragma unroll
      for (int i = 0; i < 4; ++i) {
        Is[i] = fmaf(Is[i], C_SYN_D, C_SYN_I * h1a[i]);
        V[i]  = fmaf(V[i], C_V_D, C_KMR * (Is[i] + A0v[i] + A1v[i]));
        const float Sa = glif_S(V[i]);
        A0v[i] = fmaf(A0v[i], C_A0_D, C_A0_I * Sa);
        A1v[i] = fmaf(A1v[i], C_A1_D, C_A1_I * Sa);
        spa[i] = Sa;
        Is[i] = fmaf(Is[i], C_SYN_D, C_SYN_I * h2a[i]);
        V[i]  = fmaf(V[i], C_V_D, C_KMR * (Is[i] + A0v[i] + A1v[i]));
        const float Sb = glif_S(V[i]);
        A0v[i] = fmaf(A0v[i], C_A0_D, C_A0_I * Sb);
        A1v[i] = fmaf(A1v[i], C_A1_D, C_A1_I * Sb);
        spb[i] = Sb;
      }
      // plain output stores — nobody reads `out` during the kernel
      float* outA = out + ((size_t)(2 * t) * NB + b) * N1 + mBase;
      *(float4*)outA = make_float4(spa[0], spa[1], spa[2], spa[3]);
      float* outB = out + ((size_t)(2 * t + 1) * NB + b) * N1 + mBase;
      *(float4*)outB = make_float4(spb[0], spb[1], spb[2], spb[3]);

      // tagged exchange: DUAL store. Fast (sc0 -> shared per-XCD L2) is its
      // own flag; mirror (agent atomic -> MALL) guarantees progress under
      // any placement. Both fire-and-forget; no drain, no fence.
      const size_t qoff = (size_t)(t & 1) * (NB * N1) + (size_t)b * N1 + mBase;
      const unsigned long long tg1 = ((unsigned long long)(t + 1)) << 32;
      unsigned long long tw[4];
#pragma unroll
      for (int i = 0; i < 4; ++i)
        tw[i] = tg1 | (unsigned long long)__float_as_uint(spb[i]);
      const unsigned long long qa =
          (unsigned long long)(uintptr_t)(xf + qoff);
      asm volatile("global_store_dwordx2 %0, %1, off sc0"
                   :: "v"(qa), "v"(tw[0]) : "memory");
      asm volatile("global_store_dwordx2 %0, %1, off offset:8 sc0"
                   :: "v"(qa), "v"(tw[1]) : "memory");
      asm volatile("global_store_dwordx2 %0, %1, off offset:16 sc0"
                   :: "v"(qa), "v"(tw[2]) : "memory");
      asm volatile("global_store_dwordx2 %0, %1, off offset:24 sc0"
                   :: "v"(qa), "v"(tw[3]) : "memory");
#pragma unroll
      for (int i = 0; i < 4; ++i)
        __hip_atomic_store(xs + qoff + i, tw[i], __ATOMIC_RELAXED,
                           __HIP_MEMORY_SCOPE_AGENT);
    }
    // no arrive machinery: the tagged stores ARE the readiness signal.
  }
}

// ---------------------------------------------------------------------------
extern "C" void kernel_launch(void* const* d_in, const int* in_sizes, int n_in,
                              void* d_out, int out_size, void* d_ws, size_t ws_size,
                              hipStream_t stream) {
  const float* inputs = (const float*)d_in[0];   // [1000,32,1,256]
  const float* W1     = (const float*)d_in[1];   // [512,256]
  const float* Wr     = (const float*)d_in[2];   // [512,512]
  float* out = (float*)d_out;                    // [2000,32,1,512]

  float* S0 = (float*)d_ws;                      // 32,768,000 B (as r5/r9)
  // tagged ping-pong exchange: fast + mirror, each 2 x 32 x 512 x 8B = 256KB,
  // 8B-aligned after S0. Self-cleaning via tags (poison 0xAA never matches),
  // no memset required.
  unsigned long long* xf = (unsigned long long*)((char*)d_ws +
                              (size_t)T_STEPS * NB * N0 * sizeof(float));
  unsigned long long* xs = xf + (size_t)2 * NB * N1;

  hipLaunchKernelGGL(layer0_scan, dim3((NB * N0) / 64), dim3(64), 0, stream,
                     inputs, S0);
  // PLAIN launch (r9-proven): 256 WGs on 256 CUs, full residency; bounded
  // polls guarantee termination regardless.
  hipLaunchKernelGGL(rsnn_recur, dim3(256), dim3(256), 0, stream,
                     W1, Wr, S0, out, xf, xs);
}

// Round 6
// 3160.828 us; speedup vs baseline: 3.3694x; 3.3694x over previous
//
#include <hip/hip_runtime.h>

// ---------------------------------------------------------------------------
// GLIFR RSNN on MI355X — round 11: r5-verbatim machinery + h1 IN THE SPIN
// WINDOW + redundant-barrier removal. Bit-identical arithmetic to r5.
//
// History:
//   r1 (PASSED, 11.75ms): 8 WGs/batch, cooperative, counter barrier.
//   r2/r3/r4/r7 (GHOST): cooperative launch + restructured sync -> kernel
//      never ran. Only r5's exact sync structure is proven under cooperative.
//   r5 (PASSED, 2290us recur / 2834 total): counter barrier, per-batch line.
//      Chain/step ~5500cy: [spb loads 1RTT][FMA ~550][GLIF][drain 1RTT]
//      [add 0.5RTT][detect ~1RTT]. VALUBusy 23%, HBM 4%, MfmaUtil 0.
//   r6 (REGRESSED, 2465us): h1 BEFORE the wait at step top -> serialized
//      ahead of the spin, split the load issue. Wrong window.
//   r8 (DIED): VGPR math error; single-CU-per-batch impossible (Wr 1MB vs
//      512KB regfile/CU). 8-WG split is forced; exchange is irreducible.
//   r9 (PASSED, 2590us): tagged 8B data-is-flag, agent scope. Atomic loads
//      don't coalesce; 65536 pollers at the MALL ate the saved hops.
//   r10 (PASSED, 12.6ms): sc0 "XCD-local" fast path. FETCH 644->131MB but
//      5x slower: sc0 loads act device-scope (miss/refill every poll), and
//      flagged accesses serialize. MEMORY-PATH EXPERIMENTS CLOSED.
//   r11 (this): two mechanistic fixes inside r5's proven structure:
//      (a) h1 = W1 @ S0_{t-1} depends only on precomputed S0 -> compute it
//          for step t+1 INSIDE step t's spin window (between fetch_add and
//          the poll), where all 256 threads otherwise idle ~2 RTT. Result
//          carried in 4 regs (h1p). spb loads stay at step top (unchanged).
//      (b) drop r5's post-FMA __syncthreads (S2): the next actS overwrite
//          is separated from the FMA reads by the drain AND release
//          barriers -> provably redundant.
//      Same FMA order, same shfl masks/order, same GLIF order -> outputs
//      bit-identical to r5 (absmax 0.015625 expected exactly).
//
// NOTE (r2/r3 lesson, keep): fp32 S is EXACTLY 0.0 for strongly inhibited
// neurons (V ~ -1050 -> __expf overflow -> 20/inf = 0), identically in the
// jax reference. 0x00000000 output words are legitimate.
// ---------------------------------------------------------------------------

#define T_STEPS 1000
#define NB 32
#define N0 256
#define N1 512

// fp32 constants, folded exactly like the reference's python-float scalars
#define C_SYN_D 0.95f                      // 1 - DT*KSYN
#define C_SYN_I 0.05f                      // DT*KSYN
#define C_V_D   0.99f                      // 1 - DT*KM
#define C_KMR   0.0010604453870625663f     // DT*KM*R
#define C_TH    10.986122886681098f        // SIGMA_V * log((20-5)/5)
#define C_A0_D  0.99985f                   // 1 - DT*0.003
#define C_A0_I  (-0.459f)                  // -9.18*1.0*DT
#define C_A1_D  0.995f                     // 1 - DT*0.1
#define C_A1_I  (-9.947f)                  // -198.94*1.0*DT

__device__ __forceinline__ float glif_S(float V) {
  // 20 * sigmoid((V - TH)/10)
  return 20.0f / (1.0f + __expf((C_TH - V) * 0.1f));
}

// ---------------------------------------------------------------------------
// Kernel A: layer-0 scan (r5-verbatim, proven). grid = 128 x 64.
// ---------------------------------------------------------------------------
__global__ __launch_bounds__(64)
void layer0_scan(const float* __restrict__ x, float* __restrict__ S0) {
  const int g = blockIdx.x * 64 + threadIdx.x;
  float V = 0.f, a0 = 0.f, a1 = 0.f, Is = 0.f;
  float xb[8];
#pragma unroll
  for (int i = 0; i < 8; ++i) xb[i] = x[i * (NB * N0) + g];
#pragma unroll 1
  for (int tb = 0; tb < T_STEPS / 8; ++tb) {
#pragma unroll
    for (int u = 0; u < 8; ++u) {
      const int t = tb * 8 + u;
      const float xi = xb[u];
      const int tf = t + 8;
      if (tf < T_STEPS) xb[u] = x[tf * (NB * N0) + g];
      Is = fmaf(Is, C_SYN_D, C_SYN_I * xi);
      V  = fmaf(V, C_V_D, C_KMR * (Is + a0 + a1));
      const float S = glif_S(V);
      a0 = fmaf(a0, C_A0_D, C_A0_I * S);
      a1 = fmaf(a1, C_A1_D, C_A1_I * S);
      S0[t * (NB * N0) + g] = S;
    }
  }
}

// ---------------------------------------------------------------------------
// Kernel C: recurrence. grid = 256 x 256 (cooperative, r5-verbatim launch).
// wg = b*8 + s; m-slice = [s*64, s*64+64). tid = mg*16 + kc (r5-identical).
// Per step t:
//   [top]   stage spb_{t-1} (agent atomic loads, valid since last release)
//   S1      barrier
//   [mid]   h2 partial FMAs; h2 reduce; GLIF A (h1p from prev window) +
//           GLIF B; spa/spb stores
//   [wind]  stage S0[t] -> actO; S3 drain barrier; tid0 fetch_add;
//           h1 partial FMAs + reduce (ALL threads — fills the spin idle);
//           tid0 spin; S5 release barrier
// ---------------------------------------------------------------------------
__global__ __launch_bounds__(256, 1)
void rsnn_recur(const float* __restrict__ W1, const float* __restrict__ Wr,
                const float* __restrict__ S0, float* __restrict__ out,
                unsigned* __restrict__ bar) {
  const int wg  = blockIdx.x;
  const int b   = wg >> 3;
  const int s   = wg & 7;
  const int tid = threadIdx.x;
  const int mg  = tid >> 4;
  const int kc  = tid & 15;
  const int mBase = s * 64 + mg * 4;

  __shared__ float actS[16 * 36];   // 512 spb values, padded (r5 layout)
  __shared__ float actO[16 * 20];   // 256 S0 values, padded (r5 layout)

  // --- one-time weight load into registers (r5-verbatim) ---
  float4 wr4[4][8];
  float4 w14[4][4];
#pragma unroll
  for (int i = 0; i < 4; ++i) {
    const float4* rw = (const float4*)(Wr + (size_t)(mBase + i) * N1 + kc * 32);
#pragma unroll
    for (int j = 0; j < 8; ++j) wr4[i][j] = rw[j];
    const float4* r1 = (const float4*)(W1 + (size_t)(mBase + i) * N0 + kc * 16);
#pragma unroll
    for (int j = 0; j < 4; ++j) w14[i][j] = r1[j];
  }

  float V[4]   = {0.f, 0.f, 0.f, 0.f};
  float A0v[4] = {0.f, 0.f, 0.f, 0.f};
  float A1v[4] = {0.f, 0.f, 0.f, 0.f};
  float Is[4]  = {0.f, 0.f, 0.f, 0.f};
  // h1 for step t, computed in step t-1's spin window. h1_0 = W1 @ 0 = 0.
  float h1p[4] = {0.f, 0.f, 0.f, 0.f};
  // one 128B cache line per batch's counter (r5)
  unsigned* cnt = bar + b * 32;

#pragma unroll 1
  for (int t = 0; t < T_STEPS; ++t) {
    // ---- [top] stage spb_{t-1} into LDS (loads valid since last release) --
    if (t == 0) {
      actS[(tid >> 5) * 36 + (tid & 31)] = 0.f;
      {
        const int k = tid + 256;
        actS[(k >> 5) * 36 + (k & 31)] = 0.f;
      }
    } else {
      const float* pS = out + ((size_t)(2 * t - 1) * NB + b) * N1;
      const float v0 = __hip_atomic_load(pS + tid,       __ATOMIC_RELAXED, __HIP_MEMORY_SCOPE_AGENT);
      const float v1 = __hip_atomic_load(pS + tid + 256, __ATOMIC_RELAXED, __HIP_MEMORY_SCOPE_AGENT);
      actS[(tid >> 5) * 36 + (tid & 31)] = v0;
      {
        const int k = tid + 256;
        actS[(k >> 5) * 36 + (k & 31)] = v1;
      }
    }
    __syncthreads();  // S1: actS visible

    // ---- h2 partial dots (weights from registers, acts from LDS) ----
    float h2a[4] = {0.f, 0.f, 0.f, 0.f};
    const float4* aS4 = (const float4*)actS;
#pragma unroll
    for (int j = 0; j < 8; ++j) {
      const float4 a = aS4[kc * 9 + j];
#pragma unroll
      for (int i = 0; i < 4; ++i) {
        h2a[i] = fmaf(wr4[i][j].x, a.x, h2a[i]);
        h2a[i] = fmaf(wr4[i][j].y, a.y, h2a[i]);
        h2a[i] = fmaf(wr4[i][j].z, a.z, h2a[i]);
        h2a[i] = fmaf(wr4[i][j].w, a.w, h2a[i]);
      }
    }
    // (r5's post-FMA barrier removed: next actS overwrite is separated from
    //  these reads by BOTH the drain barrier S3 and the release barrier S5.)

    // ---- reduce h2 across the 16 k-chunks (r5 masks, r5 order) ----
#pragma unroll
    for (int mask = 1; mask <= 8; mask <<= 1) {
#pragma unroll
      for (int i = 0; i < 4; ++i) {
        h2a[i] += __shfl_xor(h2a[i], mask, 64);
      }
    }

    // ---- owner lanes: GLIF A (h1p) then GLIF B (h2a) — r5-verbatim math --
    if (kc == 0) {
      float spa[4], spb[4];
#pragma unroll
      for (int i = 0; i < 4; ++i) {
        Is[i] = fmaf(Is[i], C_SYN_D, C_SYN_I * h1p[i]);
        V[i]  = fmaf(V[i], C_V_D, C_KMR * (Is[i] + A0v[i] + A1v[i]));
        const float Sa = glif_S(V[i]);
        A0v[i] = fmaf(A0v[i], C_A0_D, C_A0_I * Sa);
        A1v[i] = fmaf(A1v[i], C_A1_D, C_A1_I * Sa);
        spa[i] = Sa;
        Is[i] = fmaf(Is[i], C_SYN_D, C_SYN_I * h2a[i]);
        V[i]  = fmaf(V[i], C_V_D, C_KMR * (Is[i] + A0v[i] + A1v[i]));
        const float Sb = glif_S(V[i]);
        A0v[i] = fmaf(A0v[i], C_A0_D, C_A0_I * Sb);
        A1v[i] = fmaf(A1v[i], C_A1_D, C_A1_I * Sb);
        spb[i] = Sb;
      }
      float* outA = out + ((size_t)(2 * t) * NB + b) * N1 + mBase;
      *(float4*)outA = make_float4(spa[0], spa[1], spa[2], spa[3]);
      float* outB = out + ((size_t)(2 * t + 1) * NB + b) * N1 + mBase;
#pragma unroll
      for (int i = 0; i < 4; ++i)
        __hip_atomic_store(outB + i, spb[i], __ATOMIC_RELAXED, __HIP_MEMORY_SCOPE_AGENT);
    }

    // ---- [window] drain + arrive, with h1_{t+1} filling the spin idle ----
    if (t < T_STEPS - 1) {
      // stage S0[t] (the o0 input for step t+1's GLIF A) before the drain:
      // the load's latency overlaps the spb-store drain below.
      const float v2 = S0[(size_t)t * (NB * N0) + b * N0 + tid];
      actO[(tid >> 4) * 20 + (tid & 15)] = v2;
      __syncthreads();  // S3: compiler emits s_waitcnt vmcnt(0) before
                        // s_barrier: all lanes' write-through spb stores are
                        // globally visible before the flag increment below;
                        // also makes actO visible for the h1 FMAs.
      if (tid == 0) {
        __hip_atomic_fetch_add(cnt, 1u, __ATOMIC_RELAXED, __HIP_MEMORY_SCOPE_AGENT);
      }
      __builtin_amdgcn_sched_barrier(0);  // keep the add ahead of the h1 work

      // h1 partials + reduce for step t+1 — runs while the other 7 WGs'
      // adds propagate (the window r5 spent fully idle).
      float h1n[4] = {0.f, 0.f, 0.f, 0.f};
      const float4* aO4 = (const float4*)actO;
#pragma unroll
      for (int j = 0; j < 4; ++j) {
        const float4 a = aO4[kc * 5 + j];
#pragma unroll
        for (int i = 0; i < 4; ++i) {
          h1n[i] = fmaf(w14[i][j].x, a.x, h1n[i]);
          h1n[i] = fmaf(w14[i][j].y, a.y, h1n[i]);
          h1n[i] = fmaf(w14[i][j].z, a.z, h1n[i]);
          h1n[i] = fmaf(w14[i][j].w, a.w, h1n[i]);
        }
      }
#pragma unroll
      for (int mask = 1; mask <= 8; mask <<= 1) {
#pragma unroll
        for (int i = 0; i < 4; ++i) {
          h1n[i] += __shfl_xor(h1n[i], mask, 64);
        }
      }
#pragma unroll
      for (int i = 0; i < 4; ++i) h1p[i] = h1n[i];

      if (tid == 0) {
        const unsigned tgt = 8u * (unsigned)(t + 1);
        while (__hip_atomic_load(cnt, __ATOMIC_RELAXED, __HIP_MEMORY_SCOPE_AGENT) < tgt) {}
      }
      __syncthreads();  // S5: release — spb_t globally visible for step t+1
    }
  }
}

// ---------------------------------------------------------------------------
extern "C" void kernel_launch(void* const* d_in, const int* in_sizes, int n_in,
                              void* d_out, int out_size, void* d_ws, size_t ws_size,
                              hipStream_t stream) {
  const float* inputs = (const float*)d_in[0];   // [1000,32,1,256]
  const float* W1     = (const float*)d_in[1];   // [512,256]
  const float* Wr     = (const float*)d_in[2];   // [512,512]
  float* out = (float*)d_out;                    // [2000,32,1,512]

  float* S0 = (float*)d_ws;                                        // 32,768,000 B
  unsigned* bar = (unsigned*)((char*)d_ws +
                              (size_t)T_STEPS * NB * N0 * sizeof(float));

  // barrier counters must start at 0 every call (ws is re-poisoned to 0xAA);
  // 32 batches x 32 words = 4KB, one 128B line per batch.
  hipMemsetAsync(bar, 0, NB * 32 * sizeof(unsigned), stream);

  hipLaunchKernelGGL(layer0_scan, dim3((NB * N0) / 64), dim3(64), 0, stream,
                     inputs, S0);

  void* args[5];
  args[0] = (void*)&W1;
  args[1] = (void*)&Wr;
  args[2] = (void*)&S0;
  args[3] = (void*)&out;
  args[4] = (void*)&bar;
  // Cooperative launch (r5-verbatim): guarantees all 256 WGs (1/CU)
  // co-resident, so the per-batch spin barriers cannot deadlock.
  hipLaunchCooperativeKernel((const void*)rsnn_recur, dim3(256), dim3(256),
                             args, 0, stream);
}